// Round 1
// baseline (483.368 us; speedup 1.0000x reference)
//
#include <hip/hip_runtime.h>
#include <hip/hip_bf16.h>

// Problem: B=128, T=256, D=1024.  TOK = B*T = 32768.
// keys = x@Wk.T+bk ; queries = x@Wq.T+bq ; values = x@Wv.T+bv
// S = tril(Q K^T / 32) ; P = softmax(S) ; out = P V   (fp32 out)

typedef __attribute__((ext_vector_type(4))) float f32x4;
typedef __attribute__((ext_vector_type(8))) short s16x8;
typedef unsigned short u16;

__device__ inline u16 f2bf(float f) {
    union { __hip_bfloat16 h; u16 u; } c;
    c.h = __float2bfloat16(f);
    return c.u;
}

// ---------------- fp32 -> bf16 convert ----------------
__global__ __launch_bounds__(256) void cvt_f32_bf16(const float* __restrict__ in,
                                                    u16* __restrict__ out, int n4) {
    int stride = gridDim.x * blockDim.x;
    for (int i = blockIdx.x * blockDim.x + threadIdx.x; i < n4; i += stride) {
        float4 v = reinterpret_cast<const float4*>(in)[i];
        ushort4 o = make_ushort4(f2bf(v.x), f2bf(v.y), f2bf(v.z), f2bf(v.w));
        reinterpret_cast<ushort4*>(out)[i] = o;
    }
}

// ---------------- shared 128x128-tile BF16 MFMA mainloop ----------------
// NT layout: A rows [128][lda] contiguous along k; B^T rows [128][ldb] contiguous along k.
// 4 waves (2x2), each computes a 64x64 sub-tile as 4x4 fragments of 16x16x32.
__device__ inline void gemm_mainloop(const u16* __restrict__ Ap, const u16* __restrict__ Bp,
                                     int lda, int ldb, int kLen,
                                     u16* As, u16* Bs, f32x4 (&acc)[4][4]) {
    const int tid  = threadIdx.x;
    const int lane = tid & 63;
    const int wr   = (tid >> 7) & 1;
    const int wc   = (tid >> 6) & 1;
    const int sr   = tid >> 3;          // 0..31: staging row within 32-row group
    const int sc   = (tid & 7) << 3;    // staging col (8 bf16 = 16B per thread)

    for (int k0 = 0; k0 < kLen; k0 += 64) {
#pragma unroll
        for (int it = 0; it < 4; ++it) {
            int r = it * 32 + sr;
            *reinterpret_cast<s16x8*>(&As[r * 64 + sc]) =
                *reinterpret_cast<const s16x8*>(&Ap[(size_t)r * lda + k0 + sc]);
            *reinterpret_cast<s16x8*>(&Bs[r * 64 + sc]) =
                *reinterpret_cast<const s16x8*>(&Bp[(size_t)r * ldb + k0 + sc]);
        }
        __syncthreads();
#pragma unroll
        for (int kk = 0; kk < 64; kk += 32) {
            const int kcol = kk + (lane >> 4) * 8;
            s16x8 a[4], bfr[4];
#pragma unroll
            for (int m = 0; m < 4; ++m)
                a[m] = *reinterpret_cast<const s16x8*>(&As[(wr * 64 + m * 16 + (lane & 15)) * 64 + kcol]);
#pragma unroll
            for (int n = 0; n < 4; ++n)
                bfr[n] = *reinterpret_cast<const s16x8*>(&Bs[(wc * 64 + n * 16 + (lane & 15)) * 64 + kcol]);
#pragma unroll
            for (int m = 0; m < 4; ++m)
#pragma unroll
                for (int n = 0; n < 4; ++n)
                    acc[m][n] = __builtin_amdgcn_mfma_f32_16x16x32_bf16(a[m], bfr[n], acc[m][n], 0, 0, 0);
        }
        __syncthreads();
    }
}

// ---------------- QKV projection: out = x @ W.T + b ----------------
// grid = 256 m-tiles * 24 n-tiles (3 mats x 8 col-tiles). V is written transposed:
// Vt[b][d][t] so the PV GEMM is also NT.
__global__ __launch_bounds__(256) void qkv_gemm(const u16* __restrict__ X, const u16* __restrict__ W3,
                                                const float* __restrict__ biasK,
                                                const float* __restrict__ biasQ,
                                                const float* __restrict__ biasV,
                                                u16* __restrict__ Kb, u16* __restrict__ Qb,
                                                u16* __restrict__ Vt) {
    __shared__ u16 As[128 * 64];
    __shared__ u16 Bs[128 * 64];
    const int bid  = blockIdx.x;
    const int nt   = bid % 24;
    const int mt   = bid / 24;
    const int nmat = nt >> 3;
    const int ncol = nt & 7;
    const u16* Ap = X + (size_t)mt * 128 * 1024;
    const u16* Bp = W3 + (size_t)nmat * 1024 * 1024 + (size_t)ncol * 128 * 1024;

    f32x4 acc[4][4] = {};
    gemm_mainloop(Ap, Bp, 1024, 1024, 1024, As, Bs, acc);

    const int tid  = threadIdx.x;
    const int lane = tid & 63;
    const int wr   = (tid >> 7) & 1;
    const int wc   = (tid >> 6) & 1;
    const float* bias = (nmat == 0) ? biasK : (nmat == 1) ? biasQ : biasV;
    u16* outKQ = (nmat == 0) ? Kb : Qb;
    const int r0 = (lane >> 4) << 2;
    const int c0 = lane & 15;
#pragma unroll
    for (int m = 0; m < 4; ++m) {
#pragma unroll
        for (int n = 0; n < 4; ++n) {
            const int colg = ncol * 128 + wc * 64 + n * 16 + c0;
            const float bvv = bias[colg];
#pragma unroll
            for (int j = 0; j < 4; ++j) {
                const int rowg = mt * 128 + wr * 64 + m * 16 + r0 + j;
                const u16 hb = f2bf(acc[m][n][j] + bvv);
                if (nmat == 2) {
                    const int b = rowg >> 8, t = rowg & 255;
                    Vt[(size_t)b * 262144 + (size_t)colg * 256 + t] = hb;
                } else {
                    outKQ[(size_t)rowg * 1024 + colg] = hb;
                }
            }
        }
    }
}

// ---------------- scores: S = tril(Q K^T * 1/32) per batch ----------------
// grid = 128 batches * 3 lower-triangle 128x128 tiles.
__global__ __launch_bounds__(256) void scores_gemm(const u16* __restrict__ Qb,
                                                   const u16* __restrict__ Kb,
                                                   float* __restrict__ S) {
    __shared__ u16 As[128 * 64];
    __shared__ u16 Bs[128 * 64];
    const int bid = blockIdx.x;
    const int b   = bid / 3;
    const int rem = bid % 3;
    const int ti  = (rem == 0) ? 0 : 1;
    const int si  = (rem == 2) ? 1 : 0;
    const u16* Ap = Qb + ((size_t)b * 256 + (size_t)ti * 128) * 1024;
    const u16* Bp = Kb + ((size_t)b * 256 + (size_t)si * 128) * 1024;

    f32x4 acc[4][4] = {};
    gemm_mainloop(Ap, Bp, 1024, 1024, 1024, As, Bs, acc);

    const int tid  = threadIdx.x;
    const int lane = tid & 63;
    const int wr   = (tid >> 7) & 1;
    const int wc   = (tid >> 6) & 1;
    const int r0 = (lane >> 4) << 2;
    const int c0 = lane & 15;
    const float scale = 0.03125f;
#pragma unroll
    for (int m = 0; m < 4; ++m) {
#pragma unroll
        for (int n = 0; n < 4; ++n) {
            const int s = si * 128 + wc * 64 + n * 16 + c0;
#pragma unroll
            for (int j = 0; j < 4; ++j) {
                const int t = ti * 128 + wr * 64 + m * 16 + r0 + j;
                float v = acc[m][n][j] * scale;
                if (s > t) v = -__builtin_inff();
                S[(size_t)b * 65536 + (size_t)t * 256 + s] = v;
            }
        }
    }
}

// ---------------- row softmax -> P (bf16), zeros above diagonal ----------------
// one wave per row; 4 rows per block.
__global__ __launch_bounds__(256) void softmax_p(const float* __restrict__ S, u16* __restrict__ P) {
    const int row  = blockIdx.x * 4 + (threadIdx.x >> 6);  // 0..32767
    const int lane = threadIdx.x & 63;
    const int b = row >> 8, t = row & 255;
    const float* Sp = S + (size_t)b * 65536 + (size_t)t * 256;
    const int s0 = lane * 4;
    float4 v = reinterpret_cast<const float4*>(Sp)[lane];
    const float NEG = -__builtin_inff();
    float x0 = (s0 + 0 <= t) ? v.x : NEG;
    float x1 = (s0 + 1 <= t) ? v.y : NEG;
    float x2 = (s0 + 2 <= t) ? v.z : NEG;
    float x3 = (s0 + 3 <= t) ? v.w : NEG;
    float mx = fmaxf(fmaxf(x0, x1), fmaxf(x2, x3));
#pragma unroll
    for (int off = 1; off < 64; off <<= 1) mx = fmaxf(mx, __shfl_xor(mx, off, 64));
    float e0 = (s0 + 0 <= t) ? __expf(x0 - mx) : 0.f;
    float e1 = (s0 + 1 <= t) ? __expf(x1 - mx) : 0.f;
    float e2 = (s0 + 2 <= t) ? __expf(x2 - mx) : 0.f;
    float e3 = (s0 + 3 <= t) ? __expf(x3 - mx) : 0.f;
    float sum = e0 + e1 + e2 + e3;
#pragma unroll
    for (int off = 1; off < 64; off <<= 1) sum += __shfl_xor(sum, off, 64);
    const float inv = 1.0f / sum;
    ushort4 o = make_ushort4(f2bf(e0 * inv), f2bf(e1 * inv), f2bf(e2 * inv), f2bf(e3 * inv));
    reinterpret_cast<ushort4*>(P + (size_t)row * 256)[lane] = o;
}

// ---------------- PV: out = P @ V  (Vt is [b][d][t] so NT) ----------------
// grid = 128 batches * 2 m-tiles * 8 n-tiles; K clipped by causality.
__global__ __launch_bounds__(256) void pv_gemm(const u16* __restrict__ P, const u16* __restrict__ Vt,
                                               float* __restrict__ O) {
    __shared__ u16 As[128 * 64];
    __shared__ u16 Bs[128 * 64];
    const int bid = blockIdx.x;
    const int b   = bid >> 4;
    const int r   = bid & 15;
    const int mt  = r >> 3;
    const int ntl = r & 7;
    const u16* Ap = P + (size_t)b * 65536 + (size_t)mt * 128 * 256;     // lda 256
    const u16* Bp = Vt + (size_t)b * 262144 + (size_t)ntl * 128 * 256;  // ldb 256
    const int kmax = (mt + 1) * 128;  // rows <128 never need s>=128 (P there is 0)

    f32x4 acc[4][4] = {};
    gemm_mainloop(Ap, Bp, 256, 256, kmax, As, Bs, acc);

    const int tid  = threadIdx.x;
    const int lane = tid & 63;
    const int wr   = (tid >> 7) & 1;
    const int wc   = (tid >> 6) & 1;
    const int r0 = (lane >> 4) << 2;
    const int c0 = lane & 15;
#pragma unroll
    for (int m = 0; m < 4; ++m) {
#pragma unroll
        for (int n = 0; n < 4; ++n) {
            const int d = ntl * 128 + wc * 64 + n * 16 + c0;
#pragma unroll
            for (int j = 0; j < 4; ++j) {
                const int t = mt * 128 + wr * 64 + m * 16 + r0 + j;
                O[((size_t)b * 256 + t) * 1024 + d] = acc[m][n][j];
            }
        }
    }
}

// ---------------- launcher ----------------
extern "C" void kernel_launch(void* const* d_in, const int* in_sizes, int n_in,
                              void* d_out, int out_size, void* d_ws, size_t ws_size,
                              hipStream_t stream) {
    (void)in_sizes; (void)n_in; (void)out_size; (void)ws_size;
    const float* x  = (const float*)d_in[0];
    const float* Wk = (const float*)d_in[1];
    const float* bk = (const float*)d_in[2];
    const float* Wq = (const float*)d_in[3];
    const float* bq = (const float*)d_in[4];
    const float* Wv = (const float*)d_in[5];
    const float* bv = (const float*)d_in[6];
    float* out = (float*)d_out;
    char* ws = (char*)d_ws;

    // ws layout (bytes):
    //   [0,            67108864)  xb   bf16 x  [32768][1024]   (reused below)
    //   [67108864,     73400320)  Wb   bf16 Wk|Wq|Wv  [3][1024][1024]
    //   [73400320,    140509184)  Kb   bf16 keys    [32768][1024]
    //   [140509184,   207618048)  Qb   bf16 queries [32768][1024]
    //   [207618048,   274726912)  Vt   bf16 values^T [128][1024][256]
    //   overlay after qkv_gemm:  S f32 [128][256][256] at 0 ; P bf16 at 33554432
    u16*   xb = (u16*)(ws + 0);
    u16*   Wb = (u16*)(ws + 67108864);
    u16*   Kb = (u16*)(ws + 73400320);
    u16*   Qb = (u16*)(ws + 140509184);
    u16*   Vt = (u16*)(ws + 207618048);
    float* S  = (float*)(ws + 0);
    u16*   P  = (u16*)(ws + 33554432);

    cvt_f32_bf16<<<2048, 256, 0, stream>>>(x, xb, 33554432 / 4);
    cvt_f32_bf16<<<512, 256, 0, stream>>>(Wk, Wb, 1048576 / 4);
    cvt_f32_bf16<<<512, 256, 0, stream>>>(Wq, Wb + 1048576, 1048576 / 4);
    cvt_f32_bf16<<<512, 256, 0, stream>>>(Wv, Wb + 2097152, 1048576 / 4);
    qkv_gemm<<<6144, 256, 0, stream>>>(xb, Wb, bk, bq, bv, Kb, Qb, Vt);
    scores_gemm<<<384, 256, 0, stream>>>(Qb, Kb, S);
    softmax_p<<<8192, 256, 0, stream>>>(S, P);
    pv_gemm<<<2048, 256, 0, stream>>>(P, Vt, out);
}